// Round 12
// baseline (313.210 us; speedup 1.0000x reference)
//
#include <hip/hip_runtime.h>

#define HW 4096  // 64*64 spatial

// Static device scratch (24 MiB): qkv[m][b][o][h][w] fp32, m in {0:q,1:k,2:v}.
// Fully rewritten by qkv_proj before attn reads it on every launch -> graph-safe.
__device__ float g_qkv[3 * 8 * 64 * HW];

#if __has_builtin(__builtin_amdgcn_exp2f)
#define QSCALE 1.4426950408889634f            // prescale q by log2(e); exp2 is native v_exp_f32
__device__ __forceinline__ float fexp(float l) { return __builtin_amdgcn_exp2f(l); }
#else
#define QSCALE 1.0f
__device__ __forceinline__ float fexp(float l) { return __expf(l); }
#endif

// One block per (b,h) — UNCHANGED from R11 (proven ~30 us, near its ~25 us
// issue floor at the DVFS clock). Register-tiled: thread = (to,tw) computes
// 4o x 4w for all 3 matrices (48 independent accumulators). x via aligned
// float4 LDS reads (2-way alias = free). W rows stride 65 dwords + SCALAR
// reads: o-group bank step = 4*65 mod 32 = 4 -> 2-way = free.
__global__ __launch_bounds__(256, 2) void qkv_proj(
    const float* __restrict__ x,
    const float* __restrict__ wq,
    const float* __restrict__ wk,
    const float* __restrict__ wv)
{
    __shared__ float xs[64][64];      // [c][w] 16 KB
    __shared__ float wl[3][64][65];   // [m][o][c], stride 65
    const int t = threadIdx.x;
    const int b = blockIdx.x >> 6;
    const int h = blockIdx.x & 63;

    {
        const float* __restrict__ mats[3] = { wq, wk, wv };
        #pragma unroll
        for (int m = 0; m < 3; ++m)
            for (int i = t; i < 4096; i += 256) {
                int o = i >> 6, c = i & 63;
                wl[m][o][c] = mats[m][i];
            }
        const float* xrow = x + (size_t)b * 64 * HW + (size_t)h * 64;
        for (int i = t; i < 4096; i += 256) {
            int c = i >> 6, w = i & 63;
            xs[c][w] = xrow[(size_t)c * HW + w];
        }
    }
    __syncthreads();

    const int w0 = (t & 15) * 4;                   // w-quad
    const int o0 = (t >> 4) * 4;                   // o-quad
    float acc[3][16];
    #pragma unroll
    for (int m = 0; m < 3; ++m)
        #pragma unroll
        for (int i = 0; i < 16; ++i) acc[m][i] = 0.f;

    #pragma unroll 4
    for (int cq = 0; cq < 16; ++cq) {
        const int c0 = cq * 4;
        float xa[4][4];                            // [ci][wi]
        #pragma unroll
        for (int ci = 0; ci < 4; ++ci)
            *(float4*)&xa[ci][0] = *(const float4*)&xs[c0 + ci][w0];   // aligned b128
        #pragma unroll
        for (int m = 0; m < 3; ++m)
            #pragma unroll
            for (int oi = 0; oi < 4; ++oi) {
                #pragma unroll
                for (int ci = 0; ci < 4; ++ci) {
                    const float wv1 = wl[m][o0 + oi][c0 + ci];  // scalar b32, 2-way = free
                    #pragma unroll
                    for (int wi = 0; wi < 4; ++wi)
                        acc[m][oi * 4 + wi] = fmaf(wv1, xa[ci][wi], acc[m][oi * 4 + wi]);
                }
            }
    }

    #pragma unroll
    for (int m = 0; m < 3; ++m) {
        float* op = g_qkv + ((size_t)m * 8 + b) * (64 * HW) + (size_t)h * 64 + w0;
        #pragma unroll
        for (int oi = 0; oi < 4; ++oi) {
            float4 v = { acc[m][oi * 4 + 0], acc[m][oi * 4 + 1],
                         acc[m][oi * 4 + 2], acc[m][oi * 4 + 3] };
            *(float4*)&op[(size_t)(o0 + oi) * HW] = v;         // 256B coalesced segments
        }
    }
}

// One block per (b, o, 16-row strip): 7x7 local attention. R7 structure (which
// was correct; its 60 us came from the OCML exp2f libcall, ~9 VALU/tap) with
// native v_exp_f32 (~4 VALU/tap). Grid 2048 x 12.3 KB LDS -> 8 blocks/CU =
// 8 waves/SIMD latency hiding (R9/R11's 4x4 tile had 2 waves/SIMD AND 8-way
// bank conflicts: lane column base stepped 4 dwords -> 8 distinct banks).
// Here lanes span w = t&63 -> all 32 banks, 2-way = free.
// rel_w/rel_h dead (constant along 49-entry softmax axis -> shift-invariance).
// Zero padding + 1x1 conv => k=v=0 outside; logit q*0=0 still participates.
// k at kv[r][0..69], v at kv[r][70..139]: per-tap pair -> ds_read2_b32.
__global__ __launch_bounds__(256, 8) void attn(float* __restrict__ out)
{
    __shared__ float kv[22][140];     // 12.3 KB
    const int t = threadIdx.x;
    const int blk = blockIdx.x;
    const int quarter = blk & 3;
    const int bo = blk >> 2;
    const int b = bo >> 6, o = bo & 63;
    const int r0 = quarter * 16;

    const float* qb = g_qkv + ((size_t)(0 * 8 + b) * 64 + o) * HW;
    const float* kb = g_qkv + ((size_t)(1 * 8 + b) * 64 + o) * HW;
    const float* vb = g_qkv + ((size_t)(2 * 8 + b) * 64 + o) * HW;

    for (int i = t; i < 22 * 70; i += 256) {
        int r = i / 70, c = i - r * 70;
        int gh = r0 + r - 3, gw = c - 3;
        float kk = 0.f, vv = 0.f;
        if ((unsigned)gh < 64u && (unsigned)gw < 64u) {
            kk = kb[gh * 64 + gw];
            vv = vb[gh * 64 + gw];
        }
        kv[r][c] = kk;
        kv[r][70 + c] = vv;
    }
    __syncthreads();

    const int w = t & 63;
    const int rl = (t >> 6) * 4;      // 4 vertically adjacent pixel rows per thread

    float qv[4], den[4], num[4];
    #pragma unroll
    for (int j = 0; j < 4; ++j) {
        qv[j] = qb[(r0 + rl + j) * 64 + w] * QSCALE;
        den[j] = 0.f; num[j] = 0.f;
    }
    // halo local rows rl..rl+9; pixel j uses row rl+rr iff 0 <= rr-j < 7
    #pragma unroll
    for (int rr = 0; rr < 10; ++rr) {
        #pragma unroll
        for (int dj = 0; dj < 7; ++dj) {
            float kk = kv[rl + rr][w + dj];        // pair -> ds_read2_b32, conflict-free
            float vv = kv[rl + rr][70 + w + dj];
            #pragma unroll
            for (int j = 0; j < 4; ++j) {
                if (rr - j >= 0 && rr - j < 7) {   // compile-time predicate
                    float e = fexp(qv[j] * kk);    // v_mul + v_exp_f32
                    den[j] += e;
                    num[j] = fmaf(e, vv, num[j]);
                }
            }
        }
    }
    float* ob = out + ((size_t)(b * 64 + o)) * HW;
    #pragma unroll
    for (int j = 0; j < 4; ++j)
        ob[(r0 + rl + j) * 64 + w] = num[j] / den[j];
}

extern "C" void kernel_launch(void* const* d_in, const int* in_sizes, int n_in,
                              void* d_out, int out_size, void* d_ws, size_t ws_size,
                              hipStream_t stream)
{
    // d_in: 0=x, 1=wq, 2=wk, 3=wv (fp32), 4=rel_w, 5=rel_h (dead: softmax
    // shift-invariance), 6=kernel_size(7), 7=padding(3) hardcoded.
    qkv_proj<<<dim3(512), dim3(256), 0, stream>>>(
        (const float*)d_in[0], (const float*)d_in[1],
        (const float*)d_in[2], (const float*)d_in[3]);
    attn<<<dim3(2048), dim3(256), 0, stream>>>((float*)d_out);
}

// Round 13
// 176.196 us; speedup vs baseline: 1.7776x; 1.7776x over previous
//
#include <hip/hip_runtime.h>

#define HW 4096  // 64*64 spatial

// Static device scratch (24 MiB): qkv[m][b][o][h][w] fp32, m in {0:q,1:k,2:v}.
// Fully rewritten by qkv_proj before attn reads it on every launch -> graph-safe.
__device__ float g_qkv[3 * 8 * 64 * HW];

#if __has_builtin(__builtin_amdgcn_exp2f)
#define QSCALE 1.4426950408889634f            // prescale q by log2(e); exp2 is native v_exp_f32
__device__ __forceinline__ float fexp(float l) { return __builtin_amdgcn_exp2f(l); }
#else
#define QSCALE 1.0f
__device__ __forceinline__ float fexp(float l) { return __expf(l); }
#endif

// One block per (b,h) — UNCHANGED from R11 (proven ~30 us, near its ~25 us
// issue floor at the DVFS clock). Register-tiled: thread = (to,tw) computes
// 4o x 4w for all 3 matrices (48 independent accumulators). x via aligned
// float4 LDS reads (2-way alias = free). W rows stride 65 dwords + SCALAR
// reads: o-group bank step = 4*65 mod 32 = 4 -> 2-way = free.
__global__ __launch_bounds__(256, 2) void qkv_proj(
    const float* __restrict__ x,
    const float* __restrict__ wq,
    const float* __restrict__ wk,
    const float* __restrict__ wv)
{
    __shared__ float xs[64][64];      // [c][w] 16 KB
    __shared__ float wl[3][64][65];   // [m][o][c], stride 65
    const int t = threadIdx.x;
    const int b = blockIdx.x >> 6;
    const int h = blockIdx.x & 63;

    {
        const float* __restrict__ mats[3] = { wq, wk, wv };
        #pragma unroll
        for (int m = 0; m < 3; ++m)
            for (int i = t; i < 4096; i += 256) {
                int o = i >> 6, c = i & 63;
                wl[m][o][c] = mats[m][i];
            }
        const float* xrow = x + (size_t)b * 64 * HW + (size_t)h * 64;
        for (int i = t; i < 4096; i += 256) {
            int c = i >> 6, w = i & 63;
            xs[c][w] = xrow[(size_t)c * HW + w];
        }
    }
    __syncthreads();

    const int w0 = (t & 15) * 4;                   // w-quad
    const int o0 = (t >> 4) * 4;                   // o-quad
    float acc[3][16];
    #pragma unroll
    for (int m = 0; m < 3; ++m)
        #pragma unroll
        for (int i = 0; i < 16; ++i) acc[m][i] = 0.f;

    #pragma unroll 4
    for (int cq = 0; cq < 16; ++cq) {
        const int c0 = cq * 4;
        float xa[4][4];                            // [ci][wi]
        #pragma unroll
        for (int ci = 0; ci < 4; ++ci)
            *(float4*)&xa[ci][0] = *(const float4*)&xs[c0 + ci][w0];   // aligned b128
        #pragma unroll
        for (int m = 0; m < 3; ++m)
            #pragma unroll
            for (int oi = 0; oi < 4; ++oi) {
                #pragma unroll
                for (int ci = 0; ci < 4; ++ci) {
                    const float wv1 = wl[m][o0 + oi][c0 + ci];  // scalar b32, 2-way = free
                    #pragma unroll
                    for (int wi = 0; wi < 4; ++wi)
                        acc[m][oi * 4 + wi] = fmaf(wv1, xa[ci][wi], acc[m][oi * 4 + wi]);
                }
            }
    }

    #pragma unroll
    for (int m = 0; m < 3; ++m) {
        float* op = g_qkv + ((size_t)m * 8 + b) * (64 * HW) + (size_t)h * 64 + w0;
        #pragma unroll
        for (int oi = 0; oi < 4; ++oi) {
            float4 v = { acc[m][oi * 4 + 0], acc[m][oi * 4 + 1],
                         acc[m][oi * 4 + 2], acc[m][oi * 4 + 3] };
            *(float4*)&op[(size_t)(o0 + oi) * HW] = v;         // 256B coalesced segments
        }
    }
}

// One block per (b, o, 16-row strip): 7x7 local attention. R12 structure
// (strip blocks, full-width lanes -> conflict-free LDS, native v_exp_f32)
// with launch_bounds min-waves 8 -> 4: R12's (256,8) squeezed the allocator
// to 32 VGPRs and spilled ALL per-thread state to scratch (FETCH 231 MB,
// WRITE 430 MB, VALUBusy 7%, 227 us). (256,4) caps at 128 VGPRs — body
// needs ~70 — zero spill, still 4 waves/SIMD (2x R9/R11's latency hiding,
// which also suffered 8-way bank conflicts from 4-dword lane stride).
// rel_w/rel_h dead (constant along 49-entry softmax axis -> shift-invariance).
// Zero padding + 1x1 conv => k=v=0 outside; logit q*0=0 still participates.
// k at kv[r][0..69], v at kv[r][70..139]: per-tap pair -> ds_read2_b32.
__global__ __launch_bounds__(256, 4) void attn(float* __restrict__ out)
{
    __shared__ float kv[22][140];     // 12.3 KB
    const int t = threadIdx.x;
    const int blk = blockIdx.x;
    const int quarter = blk & 3;
    const int bo = blk >> 2;
    const int b = bo >> 6, o = bo & 63;
    const int r0 = quarter * 16;

    const float* qb = g_qkv + ((size_t)(0 * 8 + b) * 64 + o) * HW;
    const float* kb = g_qkv + ((size_t)(1 * 8 + b) * 64 + o) * HW;
    const float* vb = g_qkv + ((size_t)(2 * 8 + b) * 64 + o) * HW;

    for (int i = t; i < 22 * 70; i += 256) {
        int r = i / 70, c = i - r * 70;
        int gh = r0 + r - 3, gw = c - 3;
        float kk = 0.f, vv = 0.f;
        if ((unsigned)gh < 64u && (unsigned)gw < 64u) {
            kk = kb[gh * 64 + gw];
            vv = vb[gh * 64 + gw];
        }
        kv[r][c] = kk;
        kv[r][70 + c] = vv;
    }
    __syncthreads();

    const int w = t & 63;
    const int rl = (t >> 6) * 4;      // 4 vertically adjacent pixel rows per thread

    float qv[4], den[4], num[4];
    #pragma unroll
    for (int j = 0; j < 4; ++j) {
        qv[j] = qb[(r0 + rl + j) * 64 + w] * QSCALE;
        den[j] = 0.f; num[j] = 0.f;
    }
    // halo local rows rl..rl+9; pixel j uses row rl+rr iff 0 <= rr-j < 7
    #pragma unroll
    for (int rr = 0; rr < 10; ++rr) {
        #pragma unroll
        for (int dj = 0; dj < 7; ++dj) {
            float kk = kv[rl + rr][w + dj];        // pair -> ds_read2_b32, conflict-free
            float vv = kv[rl + rr][70 + w + dj];
            #pragma unroll
            for (int j = 0; j < 4; ++j) {
                if (rr - j >= 0 && rr - j < 7) {   // compile-time predicate
                    float e = fexp(qv[j] * kk);    // v_mul + v_exp_f32
                    den[j] += e;
                    num[j] = fmaf(e, vv, num[j]);
                }
            }
        }
    }
    float* ob = out + ((size_t)(b * 64 + o)) * HW;
    #pragma unroll
    for (int j = 0; j < 4; ++j)
        ob[(r0 + rl + j) * 64 + w] = num[j] / den[j];
}

extern "C" void kernel_launch(void* const* d_in, const int* in_sizes, int n_in,
                              void* d_out, int out_size, void* d_ws, size_t ws_size,
                              hipStream_t stream)
{
    // d_in: 0=x, 1=wq, 2=wk, 3=wv (fp32), 4=rel_w, 5=rel_h (dead: softmax
    // shift-invariance), 6=kernel_size(7), 7=padding(3) hardcoded.
    qkv_proj<<<dim3(512), dim3(256), 0, stream>>>(
        (const float*)d_in[0], (const float*)d_in[1],
        (const float*)d_in[2], (const float*)d_in[3]);
    attn<<<dim3(2048), dim3(256), 0, stream>>>((float*)d_out);
}

// Round 14
// 121.523 us; speedup vs baseline: 2.5774x; 1.4499x over previous
//
#include <hip/hip_runtime.h>

#define HW 4096  // 64*64 spatial

// Static device scratch (24 MiB): qkv[m][b][o][h][w] fp32, m in {0:q,1:k,2:v}.
// Fully rewritten by qkv_proj before attn reads it on every launch -> graph-safe.
__device__ float g_qkv[3 * 8 * 64 * HW];

#if __has_builtin(__builtin_amdgcn_exp2f)
#define QSCALE 1.4426950408889634f            // prescale q by log2(e); exp2 is native v_exp_f32
__device__ __forceinline__ float fexp(float l) { return __builtin_amdgcn_exp2f(l); }
#else
#define QSCALE 1.0f
__device__ __forceinline__ float fexp(float l) { return __expf(l); }
#endif

// One block per (b,h) — UNCHANGED from R11 (proven ~30 us, near its ~25 us
// issue floor at the DVFS clock). Register-tiled: thread = (to,tw) computes
// 4o x 4w for all 3 matrices (48 independent accumulators). x via aligned
// float4 LDS reads (2-way alias = free). W rows stride 65 dwords + SCALAR
// reads: o-group bank step = 4*65 mod 32 = 4 -> 2-way = free.
__global__ __launch_bounds__(256, 2) void qkv_proj(
    const float* __restrict__ x,
    const float* __restrict__ wq,
    const float* __restrict__ wk,
    const float* __restrict__ wv)
{
    __shared__ float xs[64][64];      // [c][w] 16 KB
    __shared__ float wl[3][64][65];   // [m][o][c], stride 65
    const int t = threadIdx.x;
    const int b = blockIdx.x >> 6;
    const int h = blockIdx.x & 63;

    {
        const float* __restrict__ mats[3] = { wq, wk, wv };
        #pragma unroll
        for (int m = 0; m < 3; ++m)
            for (int i = t; i < 4096; i += 256) {
                int o = i >> 6, c = i & 63;
                wl[m][o][c] = mats[m][i];
            }
        const float* xrow = x + (size_t)b * 64 * HW + (size_t)h * 64;
        for (int i = t; i < 4096; i += 256) {
            int c = i >> 6, w = i & 63;
            xs[c][w] = xrow[(size_t)c * HW + w];
        }
    }
    __syncthreads();

    const int w0 = (t & 15) * 4;                   // w-quad
    const int o0 = (t >> 4) * 4;                   // o-quad
    float acc[3][16];
    #pragma unroll
    for (int m = 0; m < 3; ++m)
        #pragma unroll
        for (int i = 0; i < 16; ++i) acc[m][i] = 0.f;

    #pragma unroll 4
    for (int cq = 0; cq < 16; ++cq) {
        const int c0 = cq * 4;
        float xa[4][4];                            // [ci][wi]
        #pragma unroll
        for (int ci = 0; ci < 4; ++ci)
            *(float4*)&xa[ci][0] = *(const float4*)&xs[c0 + ci][w0];   // aligned b128
        #pragma unroll
        for (int m = 0; m < 3; ++m)
            #pragma unroll
            for (int oi = 0; oi < 4; ++oi) {
                #pragma unroll
                for (int ci = 0; ci < 4; ++ci) {
                    const float wv1 = wl[m][o0 + oi][c0 + ci];  // scalar b32, 2-way = free
                    #pragma unroll
                    for (int wi = 0; wi < 4; ++wi)
                        acc[m][oi * 4 + wi] = fmaf(wv1, xa[ci][wi], acc[m][oi * 4 + wi]);
                }
            }
    }

    #pragma unroll
    for (int m = 0; m < 3; ++m) {
        float* op = g_qkv + ((size_t)m * 8 + b) * (64 * HW) + (size_t)h * 64 + w0;
        #pragma unroll
        for (int oi = 0; oi < 4; ++oi) {
            float4 v = { acc[m][oi * 4 + 0], acc[m][oi * 4 + 1],
                         acc[m][oi * 4 + 2], acc[m][oi * 4 + 3] };
            *(float4*)&op[(size_t)(o0 + oi) * HW] = v;         // 256B coalesced segments
        }
    }
}

// One block per (b, o, 16-row strip): 7x7 local attention. Strip structure +
// full-width lanes (conflict-free LDS) + native v_exp_f32. NO min-waves in
// launch_bounds: on this toolchain __launch_bounds__(256,N) gives HALF the
// expected VGPR budget (N=8 -> 32 regs R12, N=4 -> 64 regs R13) and the
// ~75-reg body spills every tap to scratch (R13: FETCH 108 MB, WRITE 194 MB).
// R7 = same structure, no min-waves: VGPR 140, zero spill (FETCH 15 MB,
// WRITE 8 MB); its 60 us was purely the OCML exp2f libcall, replaced here.
// rel_w/rel_h dead (constant along 49-entry softmax axis -> shift-invariance).
// Zero padding + 1x1 conv => k=v=0 outside; logit q*0=0 still participates.
// k at kv[r][0..69], v at kv[r][70..139]: per-tap pair -> ds_read2_b32.
__global__ __launch_bounds__(256) void attn(float* __restrict__ out)
{
    __shared__ float kv[22][140];     // 12.3 KB
    const int t = threadIdx.x;
    const int blk = blockIdx.x;
    const int quarter = blk & 3;
    const int bo = blk >> 2;
    const int b = bo >> 6, o = bo & 63;
    const int r0 = quarter * 16;

    const float* qb = g_qkv + ((size_t)(0 * 8 + b) * 64 + o) * HW;
    const float* kb = g_qkv + ((size_t)(1 * 8 + b) * 64 + o) * HW;
    const float* vb = g_qkv + ((size_t)(2 * 8 + b) * 64 + o) * HW;

    for (int i = t; i < 22 * 70; i += 256) {
        int r = i / 70, c = i - r * 70;
        int gh = r0 + r - 3, gw = c - 3;
        float kk = 0.f, vv = 0.f;
        if ((unsigned)gh < 64u && (unsigned)gw < 64u) {
            kk = kb[gh * 64 + gw];
            vv = vb[gh * 64 + gw];
        }
        kv[r][c] = kk;
        kv[r][70 + c] = vv;
    }
    __syncthreads();

    const int w = t & 63;
    const int rl = (t >> 6) * 4;      // 4 vertically adjacent pixel rows per thread

    float qv[4], den[4], num[4];
    #pragma unroll
    for (int j = 0; j < 4; ++j) {
        qv[j] = qb[(r0 + rl + j) * 64 + w] * QSCALE;
        den[j] = 0.f; num[j] = 0.f;
    }
    // halo local rows rl..rl+9; pixel j uses row rl+rr iff 0 <= rr-j < 7
    #pragma unroll
    for (int rr = 0; rr < 10; ++rr) {
        #pragma unroll
        for (int dj = 0; dj < 7; ++dj) {
            float kk = kv[rl + rr][w + dj];        // pair -> ds_read2_b32, conflict-free
            float vv = kv[rl + rr][70 + w + dj];
            #pragma unroll
            for (int j = 0; j < 4; ++j) {
                if (rr - j >= 0 && rr - j < 7) {   // compile-time predicate
                    float e = fexp(qv[j] * kk);    // v_mul + v_exp_f32
                    den[j] += e;
                    num[j] = fmaf(e, vv, num[j]);
                }
            }
        }
    }
    float* ob = out + ((size_t)(b * 64 + o)) * HW;
    #pragma unroll
    for (int j = 0; j < 4; ++j)
        ob[(r0 + rl + j) * 64 + w] = num[j] / den[j];
}

extern "C" void kernel_launch(void* const* d_in, const int* in_sizes, int n_in,
                              void* d_out, int out_size, void* d_ws, size_t ws_size,
                              hipStream_t stream)
{
    // d_in: 0=x, 1=wq, 2=wk, 3=wv (fp32), 4=rel_w, 5=rel_h (dead: softmax
    // shift-invariance), 6=kernel_size(7), 7=padding(3) hardcoded.
    qkv_proj<<<dim3(512), dim3(256), 0, stream>>>(
        (const float*)d_in[0], (const float*)d_in[1],
        (const float*)d_in[2], (const float*)d_in[3]);
    attn<<<dim3(2048), dim3(256), 0, stream>>>((float*)d_out);
}